// Round 6
// baseline (11699.527 us; speedup 1.0000x reference)
//
#include <hip/hip_runtime.h>
#include <hip/hip_bf16.h>

typedef _Float16 f16x2 __attribute__((ext_vector_type(2)));
typedef _Float16 f16x4 __attribute__((ext_vector_type(4)));
typedef _Float16 f16x8 __attribute__((ext_vector_type(8)));
typedef float f32x4 __attribute__((ext_vector_type(4)));

static constexpr int NNODE = 8192;
static constexpr int NEDGE = 262144;
static constexpr int NBATCH = 16;
static constexpr int TDIM = 15;
static constexpr int G1D = 32;
static constexpr int G2D = 64;
static constexpr int NK = 25;
static constexpr size_t NG2 = (size_t)NNODE * G2D;      // 524288
static constexpr size_t SROW = 64;                      // f16x2 per row (256 B)
static constexpr size_t SLICE = (size_t)NNODE * SROW;   // f16x2 per slice (2.1 MB)
static constexpr int GRIDP = 1024;                      // persistent grid (4 blocks/CU)

// ---------------- graph preprocessing ----------------

__global__ void deg_cnt_kernel(const int* __restrict__ ei, int* __restrict__ deg,
                               int* __restrict__ cnt) {
    int e = blockIdx.x * 256 + threadIdx.x;
    if (e < NEDGE) {
        atomicAdd(&deg[ei[e]], 1);           // row (out-degree per reference)
        atomicAdd(&cnt[ei[NEDGE + e]], 1);   // col (CSR bucket counts)
    }
}

__global__ void dinv_kernel(const int* __restrict__ deg, float* __restrict__ dinv) {
    int n = blockIdx.x * 256 + threadIdx.x;
    if (n < NNODE) dinv[n] = (deg[n] > 0) ? rsqrtf((float)deg[n]) : 0.f;
}

__global__ __launch_bounds__(1024) void scan_kernel(const int* __restrict__ cnt,
                                                    int* __restrict__ ptr) {
    __shared__ int s[1024];
    int t = threadIdx.x;
    int base = t * 8;
    int loc[8];
    int sum = 0;
#pragma unroll
    for (int i = 0; i < 8; ++i) { loc[i] = sum; sum += cnt[base + i]; }
    s[t] = sum;
    __syncthreads();
    for (int off = 1; off < 1024; off <<= 1) {
        int v = (t >= off) ? s[t - off] : 0;
        __syncthreads();
        s[t] += v;
        __syncthreads();
    }
    int prev = (t > 0) ? s[t - 1] : 0;
#pragma unroll
    for (int i = 0; i < 8; ++i) ptr[base + i] = prev + loc[i];
    if (t == 1023) ptr[NNODE] = s[1023];
}

// packed CSR entry: (src_node << 16) | fp16_bits(weight)
__global__ void fill_kernel(const int* __restrict__ ei, const int* __restrict__ ptr,
                            int* __restrict__ fill, const float* __restrict__ dinv,
                            unsigned int* __restrict__ pack) {
    int e = blockIdx.x * 256 + threadIdx.x;
    if (e < NEDGE) {
        int r = ei[e], c = ei[NEDGE + e];
        int pos = ptr[c] + atomicAdd(&fill[c], 1);
        _Float16 h = (_Float16)(-dinv[r] * dinv[c]);
        unsigned short wb = *reinterpret_cast<unsigned short*>(&h);
        pack[pos] = ((unsigned int)r << 16) | wb;
    }
}

// ---------------- FFT (real part = cosine transform) -> Tall1 k=0 slices ----------------

__global__ __launch_bounds__(256) void fft_kernel(const float* __restrict__ x,
                                                  _Float16* __restrict__ T0) {
    int n = blockIdx.x;
    __shared__ float xl[NBATCH][TDIM];
    __shared__ float ct[TDIM][TDIM];
    int t = threadIdx.x;
    if (t < NBATCH * TDIM) {
        int b = t / TDIM, s = t % TDIM;
        xl[b][s] = x[((size_t)b * NNODE + n) * TDIM + s];
    }
    if (t < TDIM * TDIM) {
        int tt = t / TDIM, s = t % TDIM;
        ct[tt][s] = cosf(6.283185307179586f * (float)((tt * s) % TDIM) / 15.0f);
    }
    __syncthreads();
    int b = t >> 4, f = t & 15;
    float a = 0.f;
    if (f < TDIM) {
#pragma unroll
        for (int s = 0; s < TDIM; ++s) a += xl[b][s] * ct[f][s];
    }
    T0[((size_t)(b >> 3) * NNODE + n) * 128 + (b & 7) * 16 + f] = (_Float16)a;
}

// ---------------- W^T fp16 (zero-padded K=32): Wt[k][g][f0..31] ----------------

__global__ void wt_kernel(const float* __restrict__ W, _Float16* __restrict__ Wt,
                          int F, int G, int total) {
    int i = blockIdx.x * 256 + threadIdx.x;
    if (i < total) {
        int f = i & 31;
        int g = (i >> 5) % G;
        int k = i / (32 * G);
        float v = (f < F) ? W[((size_t)k * F + f) * G + g] : 0.f;
        Wt[i] = (_Float16)v;
    }
}

// ---------------- persistent fused Chebyshev recursion ----------------
// ONE kernel runs all NK-1 steps with a grid-wide software barrier between
// steps (device-scope release/acquire fences -> correct for any XCD mapping;
// bid&7 sharding is a locality heuristic only). Tall layout: [k][slice][n][64].
// Co-residency: 1024 blocks, __launch_bounds__(256,4) => exactly 4 blocks/CU.

template <int Q>
__global__ __launch_bounds__(256, 4) void conv_persist(
    f16x2* __restrict__ Tall, const int* __restrict__ cptr,
    const unsigned int* __restrict__ pack, int* __restrict__ bar) {
    constexpr int G8 = 8 / Q;               // XCD-chunks per slice
    constexpr int NPB = NNODE / (G8 * 128); // nodes per block
    constexpr int NPW = NPB / 4;            // nodes per wave
    const int bid = blockIdx.x;
    const int xcd = bid & 7;
    const int s = xcd / G8;
    const int c8 = xcd % G8;
    const int sub = bid >> 3;               // [0,128)
    const int wv = threadIdx.x >> 6, lane = threadIdx.x & 63;
    const int nbase = (c8 * 128 + sub) * NPB + wv * NPW;

    for (int k = 1; k < NK; ++k) {
        const f16x2* __restrict__ src = Tall + ((size_t)(k - 1) * Q + s) * SLICE;
        const f16x2* __restrict__ prev =
            (k >= 2) ? (Tall + ((size_t)(k - 2) * Q + s) * SLICE) : nullptr;
        f16x2* __restrict__ dst = Tall + ((size_t)k * Q + s) * SLICE;

        for (int t = 0; t < NPW; ++t) {
            const int node = nbase + t;
            float a0 = 0.f, a1 = 0.f;
            const int p0 = cptr[node], p1 = cptr[node + 1];
            for (int tb = p0; tb < p1; tb += 64) {
                int m = p1 - tb;
                if (m > 64) m = 64;
                unsigned int pk = (lane < m) ? pack[tb + lane] : 0u;
                int j = 0;
                for (; j + 4 <= m; j += 4) {
                    unsigned int q0 = __builtin_amdgcn_readlane(pk, j);
                    unsigned int q1 = __builtin_amdgcn_readlane(pk, j + 1);
                    unsigned int q2 = __builtin_amdgcn_readlane(pk, j + 2);
                    unsigned int q3 = __builtin_amdgcn_readlane(pk, j + 3);
                    f16x2 r0 = src[(size_t)(q0 >> 16) * SROW + lane];
                    f16x2 r1 = src[(size_t)(q1 >> 16) * SROW + lane];
                    f16x2 r2 = src[(size_t)(q2 >> 16) * SROW + lane];
                    f16x2 r3 = src[(size_t)(q3 >> 16) * SROW + lane];
                    unsigned short b0 = (unsigned short)q0, b1 = (unsigned short)q1;
                    unsigned short b2 = (unsigned short)q2, b3 = (unsigned short)q3;
                    float w0 = (float)*reinterpret_cast<_Float16*>(&b0);
                    float w1 = (float)*reinterpret_cast<_Float16*>(&b1);
                    float w2 = (float)*reinterpret_cast<_Float16*>(&b2);
                    float w3 = (float)*reinterpret_cast<_Float16*>(&b3);
                    a0 += w0 * (float)r0[0]; a1 += w0 * (float)r0[1];
                    a0 += w1 * (float)r1[0]; a1 += w1 * (float)r1[1];
                    a0 += w2 * (float)r2[0]; a1 += w2 * (float)r2[1];
                    a0 += w3 * (float)r3[0]; a1 += w3 * (float)r3[1];
                }
                for (; j < m; ++j) {
                    unsigned int q = __builtin_amdgcn_readlane(pk, j);
                    unsigned short bw = (unsigned short)q;
                    float w = (float)*reinterpret_cast<_Float16*>(&bw);
                    f16x2 r = src[(size_t)(q >> 16) * SROW + lane];
                    a0 += w * (float)r[0]; a1 += w * (float)r[1];
                }
            }
            f16x2 o;
            if (k == 1) {
                o[0] = (_Float16)a0; o[1] = (_Float16)a1;
            } else {
                f16x2 t0 = prev[(size_t)node * SROW + lane];
                o[0] = (_Float16)(2.f * a0 - (float)t0[0]);
                o[1] = (_Float16)(2.f * a1 - (float)t0[1]);
            }
            dst[(size_t)node * SROW + lane] = o;
        }

        if (k < NK - 1) {
            // grid barrier: release -> arrive -> spin -> acquire
            __syncthreads();
            __threadfence();
            if (threadIdx.x == 0) {
                __hip_atomic_fetch_add(&bar[k], 1, __ATOMIC_RELEASE,
                                       __HIP_MEMORY_SCOPE_AGENT);
                while (__hip_atomic_load(&bar[k], __ATOMIC_RELAXED,
                                         __HIP_MEMORY_SCOPE_AGENT) < GRIDP) {
                    __builtin_amdgcn_s_sleep(8);
                }
            }
            __threadfence();
            __syncthreads();
        }
    }
}

// ---------------- deferred projections ----------------

__global__ __launch_bounds__(128) void proj1_kernel(
    const unsigned int* __restrict__ Tall, const _Float16* __restrict__ Wt,
    const float* __restrict__ bias, _Float16* __restrict__ dest) {
    constexpr int STRIDE = NK * 32 + 8;   // 808 halfs
    __shared__ _Float16 A[16 * STRIDE];
    unsigned int* Adw = reinterpret_cast<unsigned int*>(A);
    const int n = blockIdx.x;
    const int tid = threadIdx.x;

    for (int i = tid; i < 16 * STRIDE / 2; i += 128) Adw[i] = 0u;
    __syncthreads();
    for (int idx = tid; idx < NK * 128; idx += 128) {
        int k = idx >> 7, r = idx & 127;
        int h = r >> 6, j = r & 63;
        int bl = j >> 3, jp = j & 7;
        int b = h * 8 + bl;
        Adw[b * (STRIDE / 2) + k * 16 + jp] =
            Tall[((size_t)(k * 2 + h) * NNODE + n) * 64 + j];
    }
    __syncthreads();

    const int wv = tid >> 6, lane = tid & 63;
    const int m0 = lane & 15;
    const int krow = lane >> 4;
    const int k0 = krow * 8;
    const int g = wv * 16 + m0;
    const float bb = bias[g];
    f32x4 d = (f32x4){bb, bb, bb, bb};
#pragma unroll
    for (int k = 0; k < NK; ++k) {
        f16x8 af = *reinterpret_cast<const f16x8*>(&A[m0 * STRIDE + k * 32 + k0]);
        f16x8 bf = *reinterpret_cast<const f16x8*>(&Wt[((size_t)k * G1D + g) * 32 + k0]);
        d = __builtin_amdgcn_mfma_f32_16x16x32_f16(af, bf, d, 0, 0, 0);
    }
#pragma unroll
    for (int r = 0; r < 4; ++r) {
        int b = krow * 4 + r;
        _Float16 v = (_Float16)fmaxf(d[r], 0.f);
        dest[((size_t)(b >> 2) * NNODE + n) * 128 + (b & 3) * 32 + g] = v;
    }
}

__global__ __launch_bounds__(256) void proj2_kernel(
    const unsigned int* __restrict__ Tall, const _Float16* __restrict__ Wt,
    const float* __restrict__ bias, _Float16* __restrict__ dest) {
    constexpr int STRIDE = NK * 32 + 8;
    __shared__ _Float16 A[16 * STRIDE];
    unsigned int* Adw = reinterpret_cast<unsigned int*>(A);
    const int n = blockIdx.x;
    const int tid = threadIdx.x;

    for (int i = tid; i < 16 * STRIDE / 2; i += 256) Adw[i] = 0u;
    __syncthreads();
    for (int idx = tid; idx < NK * 256; idx += 256) {
        int k = idx >> 8, r = idx & 255;
        int q = r >> 6, j = r & 63;
        int bl2 = j >> 4, jp = j & 15;
        int b = q * 4 + bl2;
        Adw[b * (STRIDE / 2) + k * 16 + jp] =
            Tall[((size_t)(k * 4 + q) * NNODE + n) * 64 + j];
    }
    __syncthreads();

    const int wv = tid >> 6, lane = tid & 63;
    const int m0 = lane & 15;
    const int krow = lane >> 4;
    const int k0 = krow * 8;
    const int g = wv * 16 + m0;
    const float bb = bias[g];
    f32x4 d = (f32x4){bb, bb, bb, bb};
#pragma unroll
    for (int k = 0; k < NK; ++k) {
        f16x8 af = *reinterpret_cast<const f16x8*>(&A[m0 * STRIDE + k * 32 + k0]);
        f16x8 bf = *reinterpret_cast<const f16x8*>(&Wt[((size_t)k * G2D + g) * 32 + k0]);
        d = __builtin_amdgcn_mfma_f32_16x16x32_f16(af, bf, d, 0, 0, 0);
    }
#pragma unroll
    for (int r = 0; r < 4; ++r) {
        int b = krow * 4 + r;
        _Float16 v = (_Float16)fmaxf(d[r], 0.f);
        dest[(size_t)b * NG2 + (size_t)n * G2D + g] = v;
    }
}

// ---------------- fc ----------------
// grid = 128 chunks x 8 cgroups; block 512 thr (8 waves); wave handles 8 c's.

__global__ __launch_bounds__(512) void fc1_kernel(const _Float16* __restrict__ Hflat,
                                                  const float* __restrict__ fc1w,
                                                  float* __restrict__ partial) {
    int wave = threadIdx.x >> 6, lane = threadIdx.x & 63;
    int chunk = blockIdx.x & 127, cg = blockIdx.x >> 7;   // cg in [0,8)
    int c0 = (cg * 8 + wave) * 8;
    const float* wp = fc1w + (size_t)c0 * NG2 + (size_t)chunk * 4096;
    const _Float16* h = Hflat + (size_t)chunk * 4096;
    float acc[8][16];
#pragma unroll
    for (int c = 0; c < 8; ++c)
#pragma unroll
        for (int b = 0; b < 16; ++b) acc[c][b] = 0.f;

    for (int it = 0; it < 16; ++it) {
        int j = it * 256 + lane * 4;
        float4 wv8[8];
#pragma unroll
        for (int c = 0; c < 8; ++c)
            wv8[c] = *reinterpret_cast<const float4*>(wp + (size_t)c * NG2 + j);
#pragma unroll
        for (int b = 0; b < 16; ++b) {
            f16x4 hv = *reinterpret_cast<const f16x4*>(h + (size_t)b * NG2 + j);
            float h0 = (float)hv[0], h1 = (float)hv[1];
            float h2 = (float)hv[2], h3 = (float)hv[3];
#pragma unroll
            for (int c = 0; c < 8; ++c)
                acc[c][b] += wv8[c].x * h0 + wv8[c].y * h1 + wv8[c].z * h2 + wv8[c].w * h3;
        }
    }
#pragma unroll
    for (int c = 0; c < 8; ++c)
#pragma unroll
        for (int b = 0; b < 16; ++b) {
            float v = acc[c][b];
            for (int off = 32; off; off >>= 1) v += __shfl_down(v, off);
            if (lane == 0) partial[((size_t)chunk * 512 + c0 + c) * 16 + b] = v;
        }
}

__global__ void fc1_reduce_kernel(const float* __restrict__ partial,
                                  const float* __restrict__ fc1b, float* __restrict__ h1) {
    int i = blockIdx.x * 256 + threadIdx.x;  // 512*16
    if (i < 512 * 16) {
        int b = i & 15, c = i >> 4;
        float s = fc1b[c];
        for (int ch = 0; ch < 128; ++ch) s += partial[((size_t)ch * 512 + c) * 16 + b];
        h1[b * 512 + c] = s;
    }
}

__global__ __launch_bounds__(1024) void fc2_kernel(const float* __restrict__ h1,
                                                   const float* __restrict__ fc2w,
                                                   const float* __restrict__ fc2b,
                                                   float* __restrict__ out) {
    __shared__ float z[16][8];
    int wave = threadIdx.x >> 6, lane = threadIdx.x & 63;  // wave = b
    for (int d = 0; d < 6; ++d) {
        float acc = 0.f;
        for (int c = lane; c < 512; c += 64) acc += h1[wave * 512 + c] * fc2w[d * 512 + c];
        for (int off = 32; off; off >>= 1) acc += __shfl_down(acc, off);
        if (lane == 0) z[wave][d] = acc + fc2b[d];
    }
    __syncthreads();
    int t = threadIdx.x;
    if (t < 96) {
        int b = t / 6, d = t % 6;
        float m = z[b][0];
#pragma unroll
        for (int j = 1; j < 6; ++j) m = fmaxf(m, z[b][j]);
        float se = 0.f;
#pragma unroll
        for (int j = 0; j < 6; ++j) se += expf(z[b][j] - m);
        out[b * 6 + d] = z[b][d] - m - logf(se);
    }
}

// ---------------- host ----------------

extern "C" void kernel_launch(void* const* d_in, const int* in_sizes, int n_in,
                              void* d_out, int out_size, void* d_ws, size_t ws_size,
                              hipStream_t stream) {
    const float* x = (const float*)d_in[0];
    const int* ei = (const int*)d_in[1];
    const float* W1 = (const float*)d_in[2];
    const float* b1 = (const float*)d_in[3];
    const float* W2 = (const float*)d_in[4];
    const float* b2 = (const float*)d_in[5];
    const float* fc1w = (const float*)d_in[6];
    const float* fc1b = (const float*)d_in[7];
    const float* fc2w = (const float*)d_in[8];
    const float* fc2b = (const float*)d_in[9];
    float* out = (float*)d_out;

    char* ws = (char*)d_ws;
    size_t o = 0;
    auto alloc = [&](size_t bytes) -> void* {
        void* p = ws + o;
        o += (bytes + 255) & ~(size_t)255;
        return p;
    };
    f16x2* Tall1 = (f16x2*)alloc(NK * 2 * SLICE * 4);      // 104.9 MB: [k][h][n][64dw]
    f16x2* Tall2 = (f16x2*)alloc(NK * 4 * SLICE * 4);      // 209.7 MB: [k][q][n][64dw]
    _Float16* Hflat = (_Float16*)alloc(NBATCH * NG2 * 2);  // 16.8 MB
    float* partial = (float*)alloc((size_t)128 * 512 * 16 * 4);
    int* deg = (int*)alloc(3 * NNODE * 4);
    int* cnt = deg + NNODE;
    int* fill = cnt + NNODE;
    int* cptr = (int*)alloc((NNODE + 8) * 4);
    float* dinv = (float*)alloc(NNODE * 4);
    unsigned int* pack = (unsigned int*)alloc((size_t)NEDGE * 4);
    _Float16* Wt1 = (_Float16*)alloc(NK * G1D * 32 * 2);
    _Float16* Wt2 = (_Float16*)alloc(NK * G2D * 32 * 2);
    float* h1 = (float*)alloc(16 * 512 * 4);
    int* bar = (int*)alloc(64 * 4);

    hipMemsetAsync(deg, 0, 3 * NNODE * 4, stream);
    hipMemsetAsync(bar, 0, 64 * 4, stream);
    deg_cnt_kernel<<<NEDGE / 256, 256, 0, stream>>>(ei, deg, cnt);
    dinv_kernel<<<NNODE / 256, 256, 0, stream>>>(deg, dinv);
    scan_kernel<<<1, 1024, 0, stream>>>(cnt, cptr);
    fill_kernel<<<NEDGE / 256, 256, 0, stream>>>(ei, cptr, fill, dinv, pack);
    fft_kernel<<<NNODE, 256, 0, stream>>>(x, (_Float16*)Tall1);
    wt_kernel<<<(NK * G1D * 32 + 255) / 256, 256, 0, stream>>>(W1, Wt1, 15, G1D,
                                                               NK * G1D * 32);
    wt_kernel<<<(NK * G2D * 32 + 255) / 256, 256, 0, stream>>>(W2, Wt2, 32, G2D,
                                                               NK * G2D * 32);

    // conv1: full 24-step recursion in one persistent kernel (Q=2 slices)
    conv_persist<2><<<GRIDP, 256, 0, stream>>>(Tall1, cptr, pack, bar);
    proj1_kernel<<<NNODE, 128, 0, stream>>>((const unsigned int*)Tall1, Wt1, b1,
                                            (_Float16*)Tall2);

    // conv2: Q=4 slices
    conv_persist<4><<<GRIDP, 256, 0, stream>>>(Tall2, cptr, pack, bar + 32);
    proj2_kernel<<<NNODE, 256, 0, stream>>>((const unsigned int*)Tall2, Wt2, b2, Hflat);

    fc1_kernel<<<128 * 8, 512, 0, stream>>>(Hflat, fc1w, partial);
    fc1_reduce_kernel<<<32, 256, 0, stream>>>(partial, fc1b, h1);
    fc2_kernel<<<1, 1024, 0, stream>>>(h1, fc2w, fc2b, out);
}

// Round 8
// 1483.229 us; speedup vs baseline: 7.8879x; 7.8879x over previous
//
#include <hip/hip_runtime.h>
#include <hip/hip_bf16.h>

typedef _Float16 f16x2 __attribute__((ext_vector_type(2)));
typedef _Float16 f16x4 __attribute__((ext_vector_type(4)));
typedef _Float16 f16x8 __attribute__((ext_vector_type(8)));
typedef float f32x4 __attribute__((ext_vector_type(4)));

static constexpr int NNODE = 8192;
static constexpr int NEDGE = 262144;
static constexpr int NBATCH = 16;
static constexpr int TDIM = 15;
static constexpr int G1D = 32;
static constexpr int G2D = 64;
static constexpr int NK = 25;
static constexpr size_t NG2 = (size_t)NNODE * G2D;      // 524288
static constexpr size_t SROW = 64;                      // f16x2 per row (256 B)
static constexpr size_t SLICE = (size_t)NNODE * SROW;   // f16x2 per slice (2.1 MB)

// ---------------- graph preprocessing ----------------

__global__ void deg_cnt_kernel(const int* __restrict__ ei, int* __restrict__ deg,
                               int* __restrict__ cnt) {
    int e = blockIdx.x * 256 + threadIdx.x;
    if (e < NEDGE) {
        atomicAdd(&deg[ei[e]], 1);           // row (out-degree per reference)
        atomicAdd(&cnt[ei[NEDGE + e]], 1);   // col (CSR bucket counts)
    }
}

__global__ void dinv_kernel(const int* __restrict__ deg, float* __restrict__ dinv) {
    int n = blockIdx.x * 256 + threadIdx.x;
    if (n < NNODE) dinv[n] = (deg[n] > 0) ? rsqrtf((float)deg[n]) : 0.f;
}

__global__ __launch_bounds__(1024) void scan_kernel(const int* __restrict__ cnt,
                                                    int* __restrict__ ptr) {
    __shared__ int s[1024];
    int t = threadIdx.x;
    int base = t * 8;
    int loc[8];
    int sum = 0;
#pragma unroll
    for (int i = 0; i < 8; ++i) { loc[i] = sum; sum += cnt[base + i]; }
    s[t] = sum;
    __syncthreads();
    for (int off = 1; off < 1024; off <<= 1) {
        int v = (t >= off) ? s[t - off] : 0;
        __syncthreads();
        s[t] += v;
        __syncthreads();
    }
    int prev = (t > 0) ? s[t - 1] : 0;
#pragma unroll
    for (int i = 0; i < 8; ++i) ptr[base + i] = prev + loc[i];
    if (t == 1023) ptr[NNODE] = s[1023];
}

// packed CSR entry: (src_node << 16) | fp16_bits(weight)
__global__ void fill_kernel(const int* __restrict__ ei, const int* __restrict__ ptr,
                            int* __restrict__ fill, const float* __restrict__ dinv,
                            unsigned int* __restrict__ pack) {
    int e = blockIdx.x * 256 + threadIdx.x;
    if (e < NEDGE) {
        int r = ei[e], c = ei[NEDGE + e];
        int pos = ptr[c] + atomicAdd(&fill[c], 1);
        _Float16 h = (_Float16)(-dinv[r] * dinv[c]);
        unsigned short wb = *reinterpret_cast<unsigned short*>(&h);
        pack[pos] = ((unsigned int)r << 16) | wb;
    }
}

// ---------------- FFT (real part = cosine transform) -> Tall1 k=0 slices ----------------
// slice h (batches h*8..h*8+7), row layout: (b&7)*16 + f (f padded to 16, f=15 zero)

__global__ __launch_bounds__(256) void fft_kernel(const float* __restrict__ x,
                                                  _Float16* __restrict__ T0) {
    int n = blockIdx.x;
    __shared__ float xl[NBATCH][TDIM];
    __shared__ float ct[TDIM][TDIM];
    int t = threadIdx.x;
    if (t < NBATCH * TDIM) {
        int b = t / TDIM, s = t % TDIM;
        xl[b][s] = x[((size_t)b * NNODE + n) * TDIM + s];
    }
    if (t < TDIM * TDIM) {
        int tt = t / TDIM, s = t % TDIM;
        ct[tt][s] = cosf(6.283185307179586f * (float)((tt * s) % TDIM) / 15.0f);
    }
    __syncthreads();
    int b = t >> 4, f = t & 15;
    float a = 0.f;
    if (f < TDIM) {
#pragma unroll
        for (int s = 0; s < TDIM; ++s) a += xl[b][s] * ct[f][s];
    }
    T0[((size_t)(b >> 3) * NNODE + n) * 128 + (b & 7) * 16 + f] = (_Float16)a;
}

// ---------------- W^T fp16 (zero-padded K=32): Wt[k][g][f0..31] ----------------

__global__ void wt_kernel(const float* __restrict__ W, _Float16* __restrict__ Wt,
                          int F, int G, int total) {
    int i = blockIdx.x * 256 + threadIdx.x;
    if (i < total) {
        int f = i & 31;
        int g = (i >> 5) % G;
        int k = i / (32 * G);
        float v = (f < F) ? W[((size_t)k * F + f) * G + g] : 0.f;
        Wt[i] = (_Float16)v;
    }
}

// ---------------- Chebyshev gather step, XCD-sharded slices ----------------
// One wave per (node, slice); lane owns one dword of the 256-B row. Edge
// pack broadcast via readlane -> scalar-base row loads, 8-deep pipelined.
// dst stores and T0 loads are NON-TEMPORAL so the reused src slice (2.1 MB)
// + pack (1 MB) stay resident in the owning XCD's 4 MiB L2.

template <int Q, bool FIRST>
__global__ __launch_bounds__(256, 8) void gather_step(
    const f16x2* __restrict__ Tsrc, const f16x2* __restrict__ Tprev0,
    f16x2* __restrict__ Tdst, const int* __restrict__ cptr,
    const unsigned int* __restrict__ pack) {
    constexpr int CH = 8 / Q;                 // XCD-chunks per slice
    const int bid = blockIdx.x;
    const int xcd = bid & 7;
    const int s = xcd / CH;
    const int chunk = xcd % CH;
    const int wv = threadIdx.x >> 6, lane = threadIdx.x & 63;
    const int node = (chunk * (256 * Q) + (bid >> 3)) * 4 + wv;

    const f16x2* __restrict__ src = Tsrc + (size_t)s * SLICE;
    float a0 = 0.f, a1 = 0.f;
    const int p0 = cptr[node], p1 = cptr[node + 1];
    for (int tb = p0; tb < p1; tb += 64) {
        int m = p1 - tb;
        if (m > 64) m = 64;
        unsigned int pk = (lane < m) ? pack[tb + lane] : 0u;
        int j = 0;
        for (; j + 8 <= m; j += 8) {
            unsigned int q[8];
            f16x2 r[8];
#pragma unroll
            for (int u = 0; u < 8; ++u) q[u] = __builtin_amdgcn_readlane(pk, j + u);
#pragma unroll
            for (int u = 0; u < 8; ++u) r[u] = src[(size_t)(q[u] >> 16) * SROW + lane];
#pragma unroll
            for (int u = 0; u < 8; ++u) {
                unsigned short hb = (unsigned short)q[u];
                float w = (float)*reinterpret_cast<_Float16*>(&hb);
                a0 += w * (float)r[u][0];
                a1 += w * (float)r[u][1];
            }
        }
        for (; j < m; ++j) {
            unsigned int q = __builtin_amdgcn_readlane(pk, j);
            unsigned short hb = (unsigned short)q;
            float w = (float)*reinterpret_cast<_Float16*>(&hb);
            f16x2 r = src[(size_t)(q >> 16) * SROW + lane];
            a0 += w * (float)r[0];
            a1 += w * (float)r[1];
        }
    }

    f16x2 o;
    if (FIRST) {
        o[0] = (_Float16)a0; o[1] = (_Float16)a1;
    } else {
        f16x2 t0 = __builtin_nontemporal_load(
            &(Tprev0 + (size_t)s * SLICE)[(size_t)node * SROW + lane]);
        o[0] = (_Float16)(2.f * a0 - (float)t0[0]);
        o[1] = (_Float16)(2.f * a1 - (float)t0[1]);
    }
    __builtin_nontemporal_store(o, &(Tdst + (size_t)s * SLICE)[(size_t)node * SROW + lane]);
}

// ---------------- deferred projections ----------------
// proj1: conv1 Tall1 [k][h][n][64dw] -> relu(bias + sum_k T_k @ W1_k) -> Tall2 k=0
//        quarter-slice layout [q][n][bl2*32+g], b = q*4+bl2.

__global__ __launch_bounds__(128) void proj1_kernel(
    const unsigned int* __restrict__ Tall, const _Float16* __restrict__ Wt,
    const float* __restrict__ bias, _Float16* __restrict__ dest) {
    constexpr int STRIDE = NK * 32 + 8;   // 808 halfs
    __shared__ _Float16 A[16 * STRIDE];
    unsigned int* Adw = reinterpret_cast<unsigned int*>(A);
    const int n = blockIdx.x;
    const int tid = threadIdx.x;

    for (int i = tid; i < 16 * STRIDE / 2; i += 128) Adw[i] = 0u;
    __syncthreads();
    for (int idx = tid; idx < NK * 128; idx += 128) {
        int k = idx >> 7, r = idx & 127;
        int h = r >> 6, j = r & 63;
        int bl = j >> 3, jp = j & 7;
        int b = h * 8 + bl;
        Adw[b * (STRIDE / 2) + k * 16 + jp] =
            __builtin_nontemporal_load(&Tall[((size_t)(k * 2 + h) * NNODE + n) * 64 + j]);
    }
    __syncthreads();

    const int wv = tid >> 6, lane = tid & 63;
    const int m0 = lane & 15;
    const int krow = lane >> 4;
    const int k0 = krow * 8;
    const int g = wv * 16 + m0;
    const float bb = bias[g];
    f32x4 d = (f32x4){bb, bb, bb, bb};
#pragma unroll
    for (int k = 0; k < NK; ++k) {
        f16x8 af = *reinterpret_cast<const f16x8*>(&A[m0 * STRIDE + k * 32 + k0]);
        f16x8 bf = *reinterpret_cast<const f16x8*>(&Wt[((size_t)k * G1D + g) * 32 + k0]);
        d = __builtin_amdgcn_mfma_f32_16x16x32_f16(af, bf, d, 0, 0, 0);
    }
#pragma unroll
    for (int r = 0; r < 4; ++r) {
        int b = krow * 4 + r;
        _Float16 v = (_Float16)fmaxf(d[r], 0.f);
        dest[((size_t)(b >> 2) * NNODE + n) * 128 + (b & 3) * 32 + g] = v;
    }
}

// proj2: conv2 Tall2 [k][q][n][64dw] -> relu -> fp16 Hflat [b][n*64+g]

__global__ __launch_bounds__(256) void proj2_kernel(
    const unsigned int* __restrict__ Tall, const _Float16* __restrict__ Wt,
    const float* __restrict__ bias, _Float16* __restrict__ dest) {
    constexpr int STRIDE = NK * 32 + 8;
    __shared__ _Float16 A[16 * STRIDE];
    unsigned int* Adw = reinterpret_cast<unsigned int*>(A);
    const int n = blockIdx.x;
    const int tid = threadIdx.x;

    for (int i = tid; i < 16 * STRIDE / 2; i += 256) Adw[i] = 0u;
    __syncthreads();
    for (int idx = tid; idx < NK * 256; idx += 256) {
        int k = idx >> 8, r = idx & 255;
        int q = r >> 6, j = r & 63;
        int bl2 = j >> 4, jp = j & 15;
        int b = q * 4 + bl2;
        Adw[b * (STRIDE / 2) + k * 16 + jp] =
            __builtin_nontemporal_load(&Tall[((size_t)(k * 4 + q) * NNODE + n) * 64 + j]);
    }
    __syncthreads();

    const int wv = tid >> 6, lane = tid & 63;
    const int m0 = lane & 15;
    const int krow = lane >> 4;
    const int k0 = krow * 8;
    const int g = wv * 16 + m0;
    const float bb = bias[g];
    f32x4 d = (f32x4){bb, bb, bb, bb};
#pragma unroll
    for (int k = 0; k < NK; ++k) {
        f16x8 af = *reinterpret_cast<const f16x8*>(&A[m0 * STRIDE + k * 32 + k0]);
        f16x8 bf = *reinterpret_cast<const f16x8*>(&Wt[((size_t)k * G2D + g) * 32 + k0]);
        d = __builtin_amdgcn_mfma_f32_16x16x32_f16(af, bf, d, 0, 0, 0);
    }
#pragma unroll
    for (int r = 0; r < 4; ++r) {
        int b = krow * 4 + r;
        _Float16 v = (_Float16)fmaxf(d[r], 0.f);
        dest[(size_t)b * NG2 + (size_t)n * G2D + g] = v;
    }
}

// ---------------- fc ----------------
// grid = 128 chunks x 8 cgroups; block 512 thr (8 waves); wave handles 8 c's.

__global__ __launch_bounds__(512) void fc1_kernel(const _Float16* __restrict__ Hflat,
                                                  const float* __restrict__ fc1w,
                                                  float* __restrict__ partial) {
    int wave = threadIdx.x >> 6, lane = threadIdx.x & 63;
    int chunk = blockIdx.x & 127, cg = blockIdx.x >> 7;   // cg in [0,8)
    int c0 = (cg * 8 + wave) * 8;
    const float* wp = fc1w + (size_t)c0 * NG2 + (size_t)chunk * 4096;
    const _Float16* h = Hflat + (size_t)chunk * 4096;
    float acc[8][16];
#pragma unroll
    for (int c = 0; c < 8; ++c)
#pragma unroll
        for (int b = 0; b < 16; ++b) acc[c][b] = 0.f;

    for (int it = 0; it < 16; ++it) {
        int j = it * 256 + lane * 4;
        f32x4 wv8[8];
#pragma unroll
        for (int c = 0; c < 8; ++c)
            wv8[c] = __builtin_nontemporal_load(
                reinterpret_cast<const f32x4*>(wp + (size_t)c * NG2 + j));
#pragma unroll
        for (int b = 0; b < 16; ++b) {
            f16x4 hv = *reinterpret_cast<const f16x4*>(h + (size_t)b * NG2 + j);
            float h0 = (float)hv[0], h1 = (float)hv[1];
            float h2 = (float)hv[2], h3 = (float)hv[3];
#pragma unroll
            for (int c = 0; c < 8; ++c)
                acc[c][b] += wv8[c][0] * h0 + wv8[c][1] * h1 + wv8[c][2] * h2 + wv8[c][3] * h3;
        }
    }
#pragma unroll
    for (int c = 0; c < 8; ++c)
#pragma unroll
        for (int b = 0; b < 16; ++b) {
            float v = acc[c][b];
            for (int off = 32; off; off >>= 1) v += __shfl_down(v, off);
            if (lane == 0) partial[((size_t)chunk * 512 + c0 + c) * 16 + b] = v;
        }
}

__global__ void fc1_reduce_kernel(const float* __restrict__ partial,
                                  const float* __restrict__ fc1b, float* __restrict__ h1) {
    int i = blockIdx.x * 256 + threadIdx.x;  // 512*16
    if (i < 512 * 16) {
        int b = i & 15, c = i >> 4;
        float s = fc1b[c];
        for (int ch = 0; ch < 128; ++ch) s += partial[((size_t)ch * 512 + c) * 16 + b];
        h1[b * 512 + c] = s;
    }
}

__global__ __launch_bounds__(1024) void fc2_kernel(const float* __restrict__ h1,
                                                   const float* __restrict__ fc2w,
                                                   const float* __restrict__ fc2b,
                                                   float* __restrict__ out) {
    __shared__ float z[16][8];
    int wave = threadIdx.x >> 6, lane = threadIdx.x & 63;  // wave = b
    for (int d = 0; d < 6; ++d) {
        float acc = 0.f;
        for (int c = lane; c < 512; c += 64) acc += h1[wave * 512 + c] * fc2w[d * 512 + c];
        for (int off = 32; off; off >>= 1) acc += __shfl_down(acc, off);
        if (lane == 0) z[wave][d] = acc + fc2b[d];
    }
    __syncthreads();
    int t = threadIdx.x;
    if (t < 96) {
        int b = t / 6, d = t % 6;
        float m = z[b][0];
#pragma unroll
        for (int j = 1; j < 6; ++j) m = fmaxf(m, z[b][j]);
        float se = 0.f;
#pragma unroll
        for (int j = 0; j < 6; ++j) se += expf(z[b][j] - m);
        out[b * 6 + d] = z[b][d] - m - logf(se);
    }
}

// ---------------- host ----------------

extern "C" void kernel_launch(void* const* d_in, const int* in_sizes, int n_in,
                              void* d_out, int out_size, void* d_ws, size_t ws_size,
                              hipStream_t stream) {
    const float* x = (const float*)d_in[0];
    const int* ei = (const int*)d_in[1];
    const float* W1 = (const float*)d_in[2];
    const float* b1 = (const float*)d_in[3];
    const float* W2 = (const float*)d_in[4];
    const float* b2 = (const float*)d_in[5];
    const float* fc1w = (const float*)d_in[6];
    const float* fc1b = (const float*)d_in[7];
    const float* fc2w = (const float*)d_in[8];
    const float* fc2b = (const float*)d_in[9];
    float* out = (float*)d_out;

    char* ws = (char*)d_ws;
    size_t o = 0;
    auto alloc = [&](size_t bytes) -> void* {
        void* p = ws + o;
        o += (bytes + 255) & ~(size_t)255;
        return p;
    };
    f16x2* Tall1 = (f16x2*)alloc(NK * 2 * SLICE * 4);      // 104.9 MB: [k][h][n][64dw]
    f16x2* Tall2 = (f16x2*)alloc(NK * 4 * SLICE * 4);      // 209.7 MB: [k][q][n][64dw]
    _Float16* Hflat = (_Float16*)alloc(NBATCH * NG2 * 2);  // 16.8 MB
    float* partial = (float*)alloc((size_t)128 * 512 * 16 * 4);
    int* deg = (int*)alloc(3 * NNODE * 4);
    int* cnt = deg + NNODE;
    int* fill = cnt + NNODE;
    int* cptr = (int*)alloc((NNODE + 8) * 4);
    float* dinv = (float*)alloc(NNODE * 4);
    unsigned int* pack = (unsigned int*)alloc((size_t)NEDGE * 4);
    _Float16* Wt1 = (_Float16*)alloc(NK * G1D * 32 * 2);
    _Float16* Wt2 = (_Float16*)alloc(NK * G2D * 32 * 2);
    float* h1 = (float*)alloc(16 * 512 * 4);

    hipMemsetAsync(deg, 0, 3 * NNODE * 4, stream);
    deg_cnt_kernel<<<NEDGE / 256, 256, 0, stream>>>(ei, deg, cnt);
    dinv_kernel<<<NNODE / 256, 256, 0, stream>>>(deg, dinv);
    scan_kernel<<<1, 1024, 0, stream>>>(cnt, cptr);
    fill_kernel<<<NEDGE / 256, 256, 0, stream>>>(ei, cptr, fill, dinv, pack);
    fft_kernel<<<NNODE, 256, 0, stream>>>(x, (_Float16*)Tall1);
    wt_kernel<<<(NK * G1D * 32 + 255) / 256, 256, 0, stream>>>(W1, Wt1, 15, G1D,
                                                               NK * G1D * 32);
    wt_kernel<<<(NK * G2D * 32 + 255) / 256, 256, 0, stream>>>(W2, Wt2, 32, G2D,
                                                               NK * G2D * 32);

    // conv1 recursion: Q=2 slices, grid 4096 (one wave per node-slice)
    gather_step<2, true><<<4096, 256, 0, stream>>>(Tall1, nullptr, Tall1 + 2 * SLICE,
                                                   cptr, pack);
    for (int k = 2; k < NK; ++k) {
        gather_step<2, false><<<4096, 256, 0, stream>>>(
            Tall1 + (size_t)(k - 1) * 2 * SLICE, Tall1 + (size_t)(k - 2) * 2 * SLICE,
            Tall1 + (size_t)k * 2 * SLICE, cptr, pack);
    }
    proj1_kernel<<<NNODE, 128, 0, stream>>>((const unsigned int*)Tall1, Wt1, b1,
                                            (_Float16*)Tall2);

    // conv2 recursion: Q=4 slices, grid 8192
    gather_step<4, true><<<8192, 256, 0, stream>>>(Tall2, nullptr, Tall2 + 4 * SLICE,
                                                   cptr, pack);
    for (int k = 2; k < NK; ++k) {
        gather_step<4, false><<<8192, 256, 0, stream>>>(
            Tall2 + (size_t)(k - 1) * 4 * SLICE, Tall2 + (size_t)(k - 2) * 4 * SLICE,
            Tall2 + (size_t)k * 4 * SLICE, cptr, pack);
    }
    proj2_kernel<<<NNODE, 256, 0, stream>>>((const unsigned int*)Tall2, Wt2, b2, Hflat);

    fc1_kernel<<<128 * 8, 512, 0, stream>>>(Hflat, fc1w, partial);
    fc1_reduce_kernel<<<32, 256, 0, stream>>>(partial, fc1b, h1);
    fc2_kernel<<<1, 1024, 0, stream>>>(h1, fc2w, fc2b, out);
}